// Round 1
// baseline (273.970 us; speedup 1.0000x reference)
//
#include <hip/hip_runtime.h>
#include <hip/hip_bf16.h>
#include <math.h>

#define BATCH  4
#define NSEQ   1024
#define DIM    512
#define HEADS  8
#define DHEAD  64
#define SCALE  0.125f   /* 64^-0.5 */

// ---------------------------------------------------------------------------
// GEMM A: qkv = x[4096,512] @ w_qkv[512,1536]; scatter into q/k/v [b,h,n,d]
// 64x64 tile, 256 threads, 4x4 register blocking, K-tile 16.
// ---------------------------------------------------------------------------
__global__ __launch_bounds__(256) void gemm_qkv(const float* __restrict__ x,
                                                const float* __restrict__ w,
                                                float* __restrict__ qbuf,
                                                float* __restrict__ kbuf,
                                                float* __restrict__ vbuf) {
    __shared__ __align__(16) float As[16][68];   // A^T tile: As[k][i]
    __shared__ __align__(16) float Bs[16][68];   // B tile:   Bs[k][j]
    const int j0 = blockIdx.x * 64;              // col in [0,1536)
    const int i0 = blockIdx.y * 64;              // row in [0,4096)
    const int t  = threadIdx.x;
    const int tx = t & 15, ty = t >> 4;

    float acc[4][4] = {};

    for (int k0 = 0; k0 < 512; k0 += 16) {
        __syncthreads();
        {   // A tile (transposed store)
            const int i = t >> 2, g = (t & 3) * 4;
            const float4 a = *(const float4*)&x[(size_t)(i0 + i) * 512 + k0 + g];
            As[g + 0][i] = a.x; As[g + 1][i] = a.y;
            As[g + 2][i] = a.z; As[g + 3][i] = a.w;
        }
        {   // B tile (natural store)
            const int k = t >> 4, j = (t & 15) * 4;
            *(float4*)&Bs[k][j] = *(const float4*)&w[(size_t)(k0 + k) * 1536 + j0 + j];
        }
        __syncthreads();
        #pragma unroll
        for (int k = 0; k < 16; ++k) {
            const float4 a = *(const float4*)&As[k][ty * 4];
            const float4 b = *(const float4*)&Bs[k][tx * 4];
            const float av[4] = {a.x, a.y, a.z, a.w};
            const float bv[4] = {b.x, b.y, b.z, b.w};
            #pragma unroll
            for (int r = 0; r < 4; ++r)
                #pragma unroll
                for (int c = 0; c < 4; ++c)
                    acc[r][c] = fmaf(av[r], bv[c], acc[r][c]);
        }
    }

    // scatter: col j0 is 64-aligned -> whole tile is one of q/k/v, one head
    const int which = j0 / 512;
    const int h     = (j0 % 512) / 64;
    float* dst = (which == 0) ? qbuf : (which == 1) ? kbuf : vbuf;
    #pragma unroll
    for (int r = 0; r < 4; ++r) {
        const int i_abs = i0 + ty * 4 + r;
        const int b = i_abs >> 10, nn = i_abs & 1023;
        const float4 v4 = make_float4(acc[r][0], acc[r][1], acc[r][2], acc[r][3]);
        *(float4*)&dst[(((size_t)(b * HEADS + h) * NSEQ) + nn) * DHEAD + tx * 4] = v4;
    }
}

// ---------------------------------------------------------------------------
// Attention: per (b,h), 64-row i-tile, stream over 64-col j-tiles.
// Online softmax; dots = scale*q.k + spd; out scaled by head_keep factor.
// ---------------------------------------------------------------------------
__global__ __launch_bounds__(256) void attn_kernel(const float* __restrict__ qbuf,
                                                   const float* __restrict__ kbuf,
                                                   const float* __restrict__ vbuf,
                                                   const float* __restrict__ spd,
                                                   const float* __restrict__ head_keep,
                                                   float* __restrict__ abuf) {
    __shared__ __align__(16) float Qs[64][68];   // Q^T: Qs[d][i]
    __shared__ __align__(16) float Ks[64][68];   // K^T: Ks[d][j]
    __shared__ __align__(16) float Vs[64][68];   // V:   Vs[j][dv]
    __shared__ __align__(16) float Ps[64][68];   // P^T: Ps[j][i]

    const int bh = blockIdx.y;            // 0..31
    const int b  = bh >> 3, h = bh & 7;
    const int i0 = blockIdx.x * 64;
    const int t  = threadIdx.x;
    const int tx = t & 15, ty = t >> 4;

    const float* qh = qbuf + (size_t)bh * NSEQ * DHEAD;
    const float* kh = kbuf + (size_t)bh * NSEQ * DHEAD;
    const float* vh = vbuf + (size_t)bh * NSEQ * DHEAD;
    const float* sp = spd  + (size_t)bh * NSEQ * NSEQ;

    {   // load Q tile transposed: 4096 floats, 16/thread
        const int i = t >> 2, g = (t & 3) * 4;
        #pragma unroll
        for (int rep = 0; rep < 4; ++rep) {
            const int d0 = g + rep * 16;
            const float4 a = *(const float4*)&qh[(size_t)(i0 + i) * DHEAD + d0];
            Qs[d0 + 0][i] = a.x; Qs[d0 + 1][i] = a.y;
            Qs[d0 + 2][i] = a.z; Qs[d0 + 3][i] = a.w;
        }
    }

    float m_r[4], l_r[4], o_acc[4][4];
    #pragma unroll
    for (int r = 0; r < 4; ++r) {
        m_r[r] = -INFINITY; l_r[r] = 0.f;
        #pragma unroll
        for (int c = 0; c < 4; ++c) o_acc[r][c] = 0.f;
    }
    __syncthreads();

    for (int jt = 0; jt < 16; ++jt) {
        const int j0 = jt * 64;
        {   // K transposed + V natural
            const int i = t >> 2, g = (t & 3) * 4;
            #pragma unroll
            for (int rep = 0; rep < 4; ++rep) {
                const int d0 = g + rep * 16;
                const float4 a = *(const float4*)&kh[(size_t)(j0 + i) * DHEAD + d0];
                Ks[d0 + 0][i] = a.x; Ks[d0 + 1][i] = a.y;
                Ks[d0 + 2][i] = a.z; Ks[d0 + 3][i] = a.w;
                *(float4*)&Vs[i][d0] = *(const float4*)&vh[(size_t)(j0 + i) * DHEAD + d0];
            }
        }
        __syncthreads();

        // s[4][4] = q.k over d
        float s[4][4] = {};
        #pragma unroll 8
        for (int d = 0; d < 64; ++d) {
            const float4 a = *(const float4*)&Qs[d][ty * 4];
            const float4 bq = *(const float4*)&Ks[d][tx * 4];
            const float av[4] = {a.x, a.y, a.z, a.w};
            const float bv[4] = {bq.x, bq.y, bq.z, bq.w};
            #pragma unroll
            for (int r = 0; r < 4; ++r)
                #pragma unroll
                for (int c = 0; c < 4; ++c)
                    s[r][c] = fmaf(av[r], bv[c], s[r][c]);
        }

        // scale + spd + online softmax (row groups of 16 lanes share ty)
        #pragma unroll
        for (int r = 0; r < 4; ++r) {
            const int i_abs = i0 + ty * 4 + r;
            const float4 sp4 = *(const float4*)&sp[(size_t)i_abs * NSEQ + j0 + tx * 4];
            s[r][0] = fmaf(s[r][0], SCALE, sp4.x);
            s[r][1] = fmaf(s[r][1], SCALE, sp4.y);
            s[r][2] = fmaf(s[r][2], SCALE, sp4.z);
            s[r][3] = fmaf(s[r][3], SCALE, sp4.w);

            float mx = fmaxf(fmaxf(s[r][0], s[r][1]), fmaxf(s[r][2], s[r][3]));
            #pragma unroll
            for (int msk = 1; msk < 16; msk <<= 1)
                mx = fmaxf(mx, __shfl_xor(mx, msk));
            const float mnew = fmaxf(m_r[r], mx);
            const float fac  = __expf(m_r[r] - mnew);
            float p[4], rs = 0.f;
            #pragma unroll
            for (int c = 0; c < 4; ++c) { p[c] = __expf(s[r][c] - mnew); rs += p[c]; }
            #pragma unroll
            for (int msk = 1; msk < 16; msk <<= 1)
                rs += __shfl_xor(rs, msk);
            l_r[r] = l_r[r] * fac + rs;
            m_r[r] = mnew;
            #pragma unroll
            for (int c = 0; c < 4; ++c) {
                o_acc[r][c] *= fac;
                Ps[tx * 4 + c][ty * 4 + r] = p[c];
            }
        }
        __syncthreads();

        // o += P.V
        #pragma unroll 8
        for (int j = 0; j < 64; ++j) {
            const float4 p = *(const float4*)&Ps[j][ty * 4];
            const float4 v = *(const float4*)&Vs[j][tx * 4];
            const float pv[4] = {p.x, p.y, p.z, p.w};
            const float vv[4] = {v.x, v.y, v.z, v.w};
            #pragma unroll
            for (int r = 0; r < 4; ++r)
                #pragma unroll
                for (int c = 0; c < 4; ++c)
                    o_acc[r][c] = fmaf(pv[r], vv[c], o_acc[r][c]);
        }
        __syncthreads();
    }

    // epilogue: 1/l, head_keep rescale, write [b, n, h*64+d]
    float ksum = 0.f;
    #pragma unroll
    for (int i = 0; i < HEADS; ++i) ksum += head_keep[i];
    const float hscale = head_keep[h] * (float)HEADS / ksum;
    #pragma unroll
    for (int r = 0; r < 4; ++r) {
        const float inv = hscale / l_r[r];
        const float4 v4 = make_float4(o_acc[r][0] * inv, o_acc[r][1] * inv,
                                      o_acc[r][2] * inv, o_acc[r][3] * inv);
        const int i_abs = i0 + ty * 4 + r;
        *(float4*)&abuf[((size_t)(b * NSEQ) + i_abs) * DIM + h * DHEAD + tx * 4] = v4;
    }
}

// ---------------------------------------------------------------------------
// GEMM C: out = abuf[4096,512] @ w_out[512,512] + b_out
// ---------------------------------------------------------------------------
__global__ __launch_bounds__(256) void gemm_out(const float* __restrict__ a,
                                                const float* __restrict__ w,
                                                const float* __restrict__ bias,
                                                float* __restrict__ out) {
    __shared__ __align__(16) float As[16][68];
    __shared__ __align__(16) float Bs[16][68];
    const int j0 = blockIdx.x * 64;   // [0,512)
    const int i0 = blockIdx.y * 64;   // [0,4096)
    const int t  = threadIdx.x;
    const int tx = t & 15, ty = t >> 4;

    float acc[4][4] = {};
    for (int k0 = 0; k0 < 512; k0 += 16) {
        __syncthreads();
        {
            const int i = t >> 2, g = (t & 3) * 4;
            const float4 av = *(const float4*)&a[(size_t)(i0 + i) * 512 + k0 + g];
            As[g + 0][i] = av.x; As[g + 1][i] = av.y;
            As[g + 2][i] = av.z; As[g + 3][i] = av.w;
        }
        {
            const int k = t >> 4, j = (t & 15) * 4;
            *(float4*)&Bs[k][j] = *(const float4*)&w[(size_t)(k0 + k) * 512 + j0 + j];
        }
        __syncthreads();
        #pragma unroll
        for (int k = 0; k < 16; ++k) {
            const float4 av4 = *(const float4*)&As[k][ty * 4];
            const float4 bv4 = *(const float4*)&Bs[k][tx * 4];
            const float av[4] = {av4.x, av4.y, av4.z, av4.w};
            const float bv[4] = {bv4.x, bv4.y, bv4.z, bv4.w};
            #pragma unroll
            for (int r = 0; r < 4; ++r)
                #pragma unroll
                for (int c = 0; c < 4; ++c)
                    acc[r][c] = fmaf(av[r], bv[c], acc[r][c]);
        }
    }
    #pragma unroll
    for (int r = 0; r < 4; ++r) {
        const int i_abs = i0 + ty * 4 + r;
        const int j = j0 + tx * 4;
        const float4 bb = *(const float4*)&bias[j];
        const float4 v4 = make_float4(acc[r][0] + bb.x, acc[r][1] + bb.y,
                                      acc[r][2] + bb.z, acc[r][3] + bb.w);
        *(float4*)&out[(size_t)i_abs * 512 + j] = v4;
    }
}

extern "C" void kernel_launch(void* const* d_in, const int* in_sizes, int n_in,
                              void* d_out, int out_size, void* d_ws, size_t ws_size,
                              hipStream_t stream) {
    const float* x         = (const float*)d_in[0];
    const float* spd       = (const float*)d_in[1];
    const float* head_keep = (const float*)d_in[2];
    const float* w_qkv     = (const float*)d_in[3];
    const float* w_out     = (const float*)d_in[4];
    const float* b_out     = (const float*)d_in[5];
    float* out = (float*)d_out;

    float* ws   = (float*)d_ws;
    const size_t per = (size_t)BATCH * HEADS * NSEQ * DHEAD;  // 2M floats
    float* qbuf = ws;
    float* kbuf = qbuf + per;
    float* vbuf = kbuf + per;
    float* abuf = vbuf + per;   // [4096, 512]

    gemm_qkv<<<dim3(24, 64), 256, 0, stream>>>(x, w_qkv, qbuf, kbuf, vbuf);
    attn_kernel<<<dim3(16, 32), 256, 0, stream>>>(qbuf, kbuf, vbuf, spd, head_keep, abuf);
    gemm_out<<<dim3(8, 64), 256, 0, stream>>>(abuf, w_out, b_out, out);
}

// Round 4
// 88.037 us; speedup vs baseline: 3.1120x; 3.1120x over previous
//
#include <hip/hip_runtime.h>
#include <math.h>

#define NSEQ   1024
#define HEADS  8
#define DHEAD  64
#define SCALE  0.125f

typedef unsigned int u32;
typedef unsigned short u16;
typedef short short8 __attribute__((ext_vector_type(8)));   // 8 bf16 (4 VGPRs)
typedef float f32x4  __attribute__((ext_vector_type(4)));
typedef float f32x16 __attribute__((ext_vector_type(16)));

__device__ __forceinline__ u16 f2bf(float f) {
    u32 u = __float_as_uint(f);
    return (u16)((u + 0x7fffu + ((u >> 16) & 1u)) >> 16);   // RNE
}
__device__ __forceinline__ u32 pk2(float lo, float hi) {
    return (u32)f2bf(lo) | ((u32)f2bf(hi) << 16);
}
__device__ __forceinline__ f32x4 mfma16(short8 a, short8 b, f32x4 c) {
    return __builtin_amdgcn_mfma_f32_16x16x32_bf16(a, b, c, 0, 0, 0);
}
__device__ __forceinline__ f32x16 mfma32(short8 a, short8 b, f32x16 c) {
    return __builtin_amdgcn_mfma_f32_32x32x16_bf16(a, b, c, 0, 0, 0);
}

// ---------------------------------------------------------------------------
// fp32 -> bf16 straight convert (x)
// ---------------------------------------------------------------------------
__global__ __launch_bounds__(256) void conv_bf16(const float* __restrict__ in,
                                                 u16* __restrict__ out, int n) {
    int i = (blockIdx.x * 256 + threadIdx.x) * 8;
    if (i >= n) return;
    float4 a = *(const float4*)&in[i];
    float4 b = *(const float4*)&in[i + 4];
    short8 v;
    v[0] = (short)f2bf(a.x); v[1] = (short)f2bf(a.y);
    v[2] = (short)f2bf(a.z); v[3] = (short)f2bf(a.w);
    v[4] = (short)f2bf(b.x); v[5] = (short)f2bf(b.y);
    v[6] = (short)f2bf(b.z); v[7] = (short)f2bf(b.w);
    *(short8*)&out[i] = v;
}

// ---------------------------------------------------------------------------
// fp32 [K][N] -> bf16 [N][K] transpose-convert (weights)
// ---------------------------------------------------------------------------
__global__ __launch_bounds__(256) void transpose_bf16(const float* __restrict__ in,
                                                      u16* __restrict__ out,
                                                      int K, int N) {
    __shared__ float T[64][65];
    const int n0 = blockIdx.x * 64, k0 = blockIdx.y * 64;
    const int t = threadIdx.x;
    #pragma unroll
    for (int rep = 0; rep < 4; ++rep) {
        int r = rep * 16 + (t >> 4), c = (t & 15) * 4;
        float4 v = *(const float4*)&in[(size_t)(k0 + r) * N + n0 + c];
        T[r][c + 0] = v.x; T[r][c + 1] = v.y; T[r][c + 2] = v.z; T[r][c + 3] = v.w;
    }
    __syncthreads();
    const int nl = t >> 2, kb = (t & 3) * 16;
    short8 s0, s1;
    #pragma unroll
    for (int e = 0; e < 8; ++e) s0[e] = (short)f2bf(T[kb + e][nl]);
    #pragma unroll
    for (int e = 0; e < 8; ++e) s1[e] = (short)f2bf(T[kb + 8 + e][nl]);
    *(short8*)&out[(size_t)(n0 + nl) * K + k0 + kb] = s0;
    *(short8*)&out[(size_t)(n0 + nl) * K + k0 + kb + 8] = s1;
}

// ---------------------------------------------------------------------------
// GEMM qkv: C = x_bf[4096,512] @ w  (w given transposed: wT[1536][512] bf16)
// 128x128 tile, 4 waves (2x2), 16x16x32 MFMA, BK=32, padded LDS (+8 shorts).
// q,k tiles -> [b,h,n,64] bf16.  v tiles -> operand-swapped C^T -> vT[b,h,64,n].
// ---------------------------------------------------------------------------
__global__ __launch_bounds__(256) void gemm_qkv_mfma(const u16* __restrict__ xb,
                                                     const u16* __restrict__ wT,
                                                     u16* __restrict__ qb,
                                                     u16* __restrict__ kb,
                                                     u16* __restrict__ vT) {
    __shared__ u16 As[128][40];
    __shared__ u16 Bs[128][40];
    const int t = threadIdx.x, lane = t & 63, w = t >> 6;
    const int wm = w >> 1, wn = w & 1;
    const int l15 = lane & 15, l4 = lane >> 4;
    const int j0 = blockIdx.x * 128, i0 = blockIdx.y * 128;
    const int which = j0 / 512;           // 0=q 1=k 2=v (uniform per block)
    const int b = i0 >> 10;

    f32x4 acc[4][4];
    #pragma unroll
    for (int m = 0; m < 4; ++m)
        #pragma unroll
        for (int n = 0; n < 4; ++n) acc[m][n] = (f32x4){0.f, 0.f, 0.f, 0.f};

    const u16* Abase = (which < 2) ? &As[0][0] : &Bs[0][0];
    const u16* Bbase = (which < 2) ? &Bs[0][0] : &As[0][0];

    short8 ra[2], rb[2];
    #pragma unroll
    for (int rep = 0; rep < 2; ++rep) {
        int row = rep * 64 + (t >> 2), c8 = (t & 3) * 8;
        ra[rep] = *(const short8*)&xb[(size_t)(i0 + row) * 512 + c8];
        rb[rep] = *(const short8*)&wT[(size_t)(j0 + row) * 512 + c8];
    }

    for (int kt = 0; kt < 16; ++kt) {
        __syncthreads();
        #pragma unroll
        for (int rep = 0; rep < 2; ++rep) {
            int row = rep * 64 + (t >> 2), c8 = (t & 3) * 8;
            *(short8*)&As[row][c8] = ra[rep];
            *(short8*)&Bs[row][c8] = rb[rep];
        }
        __syncthreads();
        if (kt < 15) {
            int k0 = (kt + 1) * 32;
            #pragma unroll
            for (int rep = 0; rep < 2; ++rep) {
                int row = rep * 64 + (t >> 2), c8 = (t & 3) * 8;
                ra[rep] = *(const short8*)&xb[(size_t)(i0 + row) * 512 + k0 + c8];
                rb[rep] = *(const short8*)&wT[(size_t)(j0 + row) * 512 + k0 + c8];
            }
        }
        short8 af[4], bf[4];
        #pragma unroll
        for (int m = 0; m < 4; ++m)
            af[m] = *(const short8*)&Abase[(size_t)(wm * 64 + m * 16 + l15) * 40 + l4 * 8];
        #pragma unroll
        for (int n = 0; n < 4; ++n)
            bf[n] = *(const short8*)&Bbase[(size_t)(wn * 64 + n * 16 + l15) * 40 + l4 * 8];
        #pragma unroll
        for (int m = 0; m < 4; ++m)
            #pragma unroll
            for (int n = 0; n < 4; ++n)
                acc[m][n] = mfma16(af[m], bf[n], acc[m][n]);
    }

    if (which < 2) {
        u16* dst = (which == 0) ? qb : kb;
        #pragma unroll
        for (int m = 0; m < 4; ++m)
            #pragma unroll
            for (int n = 0; n < 4; ++n) {
                int col = j0 + wn * 64 + n * 16 + l15;
                int h = (col & 511) >> 6, d = col & 63;
                #pragma unroll
                for (int r = 0; r < 4; ++r) {
                    int tok = i0 + wm * 64 + m * 16 + l4 * 4 + r;
                    dst[(((size_t)(b * HEADS + h)) * NSEQ + (tok & 1023)) * DHEAD + d] =
                        f2bf(acc[m][n][r]);
                }
            }
    } else {
        #pragma unroll
        for (int m = 0; m < 4; ++m)
            #pragma unroll
            for (int n = 0; n < 4; ++n) {
                int tok = i0 + wn * 64 + n * 16 + l15;
                #pragma unroll
                for (int r = 0; r < 4; ++r) {
                    int j = j0 + wm * 64 + m * 16 + l4 * 4 + r - 1024;  // v-dim
                    int h = j >> 6, d = j & 63;
                    vT[(((size_t)(b * HEADS + h)) * DHEAD + d) * NSEQ + (tok & 1023)] =
                        f2bf(acc[m][n][r]);
                }
            }
    }
}

// ---------------------------------------------------------------------------
// Flash attention, swapped-QK^T form.  Block = (b,h) x 128 i-rows, 4 waves,
// each wave owns 32 i-columns of S^T.  j-loop over 32-key tiles.
// S^T = mfma32(K, Q); softmax in-register (lane-local row), P assembled via
// pack+shfl_xor(32); O += mfma32(P, V^T).
// ---------------------------------------------------------------------------
__global__ __launch_bounds__(256) void attn_mfma(const u16* __restrict__ qb,
                                                 const u16* __restrict__ kb,
                                                 const u16* __restrict__ vT,
                                                 const float* __restrict__ spd,
                                                 const float* __restrict__ head_keep,
                                                 u16* __restrict__ ab) {
    __shared__ u16 Qs[128][72];
    __shared__ u16 Ks[32][72];
    __shared__ u16 Vs[64][40];
    __shared__ float Ss[128][33];

    const int t = threadIdx.x, lane = t & 63, w = t >> 6;
    const int hi = lane >> 5, li = lane & 31;
    const int bh = blockIdx.y, b = bh >> 3, h = bh & 7;
    const int i0 = blockIdx.x * 128;

    const u16* qh = qb + (size_t)bh * NSEQ * DHEAD;
    const u16* kh = kb + (size_t)bh * NSEQ * DHEAD;
    const u16* vh = vT + (size_t)bh * DHEAD * NSEQ;
    const float* sp = spd + (size_t)bh * NSEQ * NSEQ;

    // Q tile [128][64]
    #pragma unroll
    for (int rep = 0; rep < 4; ++rep) {
        int row = rep * 32 + (t >> 3), c8 = (t & 7) * 8;
        *(short8*)&Qs[row][c8] = *(const short8*)&qh[(size_t)(i0 + row) * DHEAD + c8];
    }

    float m_s = -1e30f, l_s = 0.f;
    f32x16 o0 = {}, o1 = {};
    #pragma unroll
    for (int r = 0; r < 16; ++r) { o0[r] = 0.f; o1[r] = 0.f; }

    // prologue loads (jt = 0)
    short8 rk, rv;
    float4 rs[4];
    {
        int row = t >> 3, c8 = (t & 7) * 8;
        rk = *(const short8*)&kh[(size_t)row * DHEAD + c8];
        int dr = t >> 2, c8v = (t & 3) * 8;
        rv = *(const short8*)&vh[(size_t)dr * NSEQ + c8v];
        #pragma unroll
        for (int rep = 0; rep < 4; ++rep) {
            int rrow = rep * 32 + (t >> 3), c = (t & 7) * 4;
            rs[rep] = *(const float4*)&sp[(size_t)(i0 + rrow) * NSEQ + c];
        }
    }

    for (int jt = 0; jt < 32; ++jt) {
        __syncthreads();   // protect previous iteration's LDS reads (and Q writes at jt=0)
        {
            int row = t >> 3, c8 = (t & 7) * 8;
            *(short8*)&Ks[row][c8] = rk;
            int dr = t >> 2, c8v = (t & 3) * 8;
            *(short8*)&Vs[dr][c8v] = rv;
            #pragma unroll
            for (int rep = 0; rep < 4; ++rep) {
                int rrow = rep * 32 + (t >> 3), c = (t & 7) * 4;
                Ss[rrow][c + 0] = rs[rep].x; Ss[rrow][c + 1] = rs[rep].y;
                Ss[rrow][c + 2] = rs[rep].z; Ss[rrow][c + 3] = rs[rep].w;
            }
        }
        __syncthreads();
        if (jt < 31) {   // prefetch next tile while computing
            int j0n = (jt + 1) * 32;
            int row = t >> 3, c8 = (t & 7) * 8;
            rk = *(const short8*)&kh[(size_t)(j0n + row) * DHEAD + c8];
            int dr = t >> 2, c8v = (t & 3) * 8;
            rv = *(const short8*)&vh[(size_t)dr * NSEQ + j0n + c8v];
            #pragma unroll
            for (int rep = 0; rep < 4; ++rep) {
                int rrow = rep * 32 + (t >> 3), c = (t & 7) * 4;
                rs[rep] = *(const float4*)&sp[(size_t)(i0 + rrow) * NSEQ + j0n + c];
            }
        }

        // S^T[key][i] = sum_d K[key][d] Q[i][d]
        f32x16 s = {};
        #pragma unroll
        for (int r = 0; r < 16; ++r) s[r] = 0.f;
        #pragma unroll
        for (int ds = 0; ds < 4; ++ds) {
            short8 ak = *(const short8*)&Ks[li][ds * 16 + hi * 8];
            short8 bq = *(const short8*)&Qs[w * 32 + li][ds * 16 + hi * 8];
            s = mfma32(ak, bq, s);
        }

        // softmax (lane li owns i-column w*32+li; regs = 16 keys, half split)
        float p[16], pmax = -1e30f;
        #pragma unroll
        for (int r = 0; r < 16; ++r) {
            int key = (r & 3) + 8 * (r >> 2) + 4 * hi;
            float v = s[r] * SCALE + Ss[w * 32 + li][key];
            p[r] = v;
            pmax = fmaxf(pmax, v);
        }
        pmax = fmaxf(pmax, __shfl_xor(pmax, 32));
        float mnew = fmaxf(m_s, pmax);
        float fac = __expf(m_s - mnew);
        m_s = mnew;
        float rsum = 0.f;
        #pragma unroll
        for (int r = 0; r < 16; ++r) { p[r] = __expf(p[r] - mnew); rsum += p[r]; }
        rsum += __shfl_xor(rsum, 32);
        l_s = l_s * fac + rsum;

        // rescale O rows by their fac (row i lives in lane i of lo half)
        #pragma unroll
        for (int r = 0; r < 16; ++r) {
            int ip = (r & 3) + 8 * (r >> 2) + 4 * hi;
            float fr = __shfl(fac, ip);
            o0[r] *= fr; o1[r] *= fr;
        }

        // P fragments: A[i=li][key] for keystep ks, keys ks*16 + hi*8 + 0..7
        short8 pf[2];
        #pragma unroll
        for (int ks = 0; ks < 2; ++ks) {
            int rb = ks * 8;
            u32 a0 = pk2(p[rb + 0], p[rb + 1]);
            u32 a1 = pk2(p[rb + 2], p[rb + 3]);
            u32 a2 = pk2(p[rb + 4], p[rb + 5]);
            u32 a3 = pk2(p[rb + 6], p[rb + 7]);
            u32 x0 = (u32)__shfl_xor((int)a0, 32);
            u32 x1 = (u32)__shfl_xor((int)a1, 32);
            u32 x2 = (u32)__shfl_xor((int)a2, 32);
            u32 x3 = (u32)__shfl_xor((int)a3, 32);
            union { u32 u[4]; short8 v; } c4;
            c4.u[0] = hi ? x2 : a0;
            c4.u[1] = hi ? x3 : a1;
            c4.u[2] = hi ? a2 : x0;
            c4.u[3] = hi ? a3 : x1;
            pf[ks] = c4.v;
        }

        // O += P * V   (B-frag: V^T[d][key], d = df*32 + li)
        #pragma unroll
        for (int ks = 0; ks < 2; ++ks) {
            short8 v0f = *(const short8*)&Vs[li][ks * 16 + hi * 8];
            short8 v1f = *(const short8*)&Vs[32 + li][ks * 16 + hi * 8];
            o0 = mfma32(pf[ks], v0f, o0);
            o1 = mfma32(pf[ks], v1f, o1);
        }
    }

    // epilogue
    float ksum = 0.f;
    #pragma unroll
    for (int i = 0; i < HEADS; ++i) ksum += head_keep[i];
    const float hscale = head_keep[h] * (float)HEADS / ksum;
    const float inv = hscale / l_s;   // per-i value held by lane li (both halves)
    #pragma unroll
    for (int r = 0; r < 16; ++r) {
        int ip = (r & 3) + 8 * (r >> 2) + 4 * hi;
        float invr = __shfl(inv, ip);
        int tok = i0 + w * 32 + ip;
        size_t base = ((size_t)(b * NSEQ) + tok) * 512 + h * DHEAD;
        ab[base + li]      = f2bf(o0[r] * invr);
        ab[base + 32 + li] = f2bf(o1[r] * invr);
    }
}

// ---------------------------------------------------------------------------
// GEMM out: out[4096,512] = abuf_bf[4096,512] @ w_out (given as woutT[512][512])
// + bias, fp32 output.
// ---------------------------------------------------------------------------
__global__ __launch_bounds__(256) void gemm_out_mfma(const u16* __restrict__ abuf,
                                                     const u16* __restrict__ wT,
                                                     const float* __restrict__ bias,
                                                     float* __restrict__ out) {
    __shared__ u16 As[128][40];
    __shared__ u16 Bs[128][40];
    const int t = threadIdx.x, lane = t & 63, w = t >> 6;
    const int wm = w >> 1, wn = w & 1;
    const int l15 = lane & 15, l4 = lane >> 4;
    const int j0 = blockIdx.x * 128, i0 = blockIdx.y * 128;

    f32x4 acc[4][4];
    #pragma unroll
    for (int m = 0; m < 4; ++m)
        #pragma unroll
        for (int n = 0; n < 4; ++n) acc[m][n] = (f32x4){0.f, 0.f, 0.f, 0.f};

    short8 ra[2], rb[2];
    #pragma unroll
    for (int rep = 0; rep < 2; ++rep) {
        int row = rep * 64 + (t >> 2), c8 = (t & 3) * 8;
        ra[rep] = *(const short8*)&abuf[(size_t)(i0 + row) * 512 + c8];
        rb[rep] = *(const short8*)&wT[(size_t)(j0 + row) * 512 + c8];
    }

    for (int kt = 0; kt < 16; ++kt) {
        __syncthreads();
        #pragma unroll
        for (int rep = 0; rep < 2; ++rep) {
            int row = rep * 64 + (t >> 2), c8 = (t & 3) * 8;
            *(short8*)&As[row][c8] = ra[rep];
            *(short8*)&Bs[row][c8] = rb[rep];
        }
        __syncthreads();
        if (kt < 15) {
            int k0 = (kt + 1) * 32;
            #pragma unroll
            for (int rep = 0; rep < 2; ++rep) {
                int row = rep * 64 + (t >> 2), c8 = (t & 3) * 8;
                ra[rep] = *(const short8*)&abuf[(size_t)(i0 + row) * 512 + k0 + c8];
                rb[rep] = *(const short8*)&wT[(size_t)(j0 + row) * 512 + k0 + c8];
            }
        }
        short8 af[4], bf[4];
        #pragma unroll
        for (int m = 0; m < 4; ++m)
            af[m] = *(const short8*)&As[wm * 64 + m * 16 + l15][l4 * 8];
        #pragma unroll
        for (int n = 0; n < 4; ++n)
            bf[n] = *(const short8*)&Bs[wn * 64 + n * 16 + l15][l4 * 8];
        #pragma unroll
        for (int m = 0; m < 4; ++m)
            #pragma unroll
            for (int n = 0; n < 4; ++n)
                acc[m][n] = mfma16(af[m], bf[n], acc[m][n]);
    }

    #pragma unroll
    for (int m = 0; m < 4; ++m)
        #pragma unroll
        for (int n = 0; n < 4; ++n) {
            int col = j0 + wn * 64 + n * 16 + l15;
            float bb = bias[col];
            #pragma unroll
            for (int r = 0; r < 4; ++r) {
                int row = i0 + wm * 64 + m * 16 + l4 * 4 + r;
                out[(size_t)row * 512 + col] = acc[m][n][r] + bb;
            }
        }
}

extern "C" void kernel_launch(void* const* d_in, const int* in_sizes, int n_in,
                              void* d_out, int out_size, void* d_ws, size_t ws_size,
                              hipStream_t stream) {
    const float* x         = (const float*)d_in[0];
    const float* spd       = (const float*)d_in[1];
    const float* head_keep = (const float*)d_in[2];
    const float* w_qkv     = (const float*)d_in[3];
    const float* w_out     = (const float*)d_in[4];
    const float* b_out     = (const float*)d_in[5];
    float* out = (float*)d_out;

    char* ws = (char*)d_ws;
    u16* x_bf   = (u16*)(ws);                       // 4096*512
    u16* wqkvT  = (u16*)(ws + (4u << 20));          // 1536*512
    u16* woutT  = (u16*)(ws + (4u << 20) + 1572864);// 512*512
    u16* qb     = (u16*)(ws + (6u << 20));          // 32*1024*64
    u16* kb     = (u16*)(ws + (10u << 20));
    u16* vT     = (u16*)(ws + (14u << 20));
    u16* ab     = (u16*)(ws + (18u << 20));         // 4096*512

    conv_bf16<<<1024, 256, 0, stream>>>(x, x_bf, 4096 * 512);
    transpose_bf16<<<dim3(24, 8), 256, 0, stream>>>(w_qkv, wqkvT, 512, 1536);
    transpose_bf16<<<dim3(8, 8), 256, 0, stream>>>(w_out, woutT, 512, 512);
    gemm_qkv_mfma<<<dim3(12, 32), 256, 0, stream>>>(x_bf, wqkvT, qb, kb, vT);
    attn_mfma<<<dim3(8, 32), 256, 0, stream>>>(qb, kb, vT, spd, head_keep, ab);
    gemm_out_mfma<<<dim3(4, 32), 256, 0, stream>>>(ab, woutT, b_out, out);
}

// Round 5
// 81.186 us; speedup vs baseline: 3.3746x; 1.0844x over previous
//
#include <hip/hip_runtime.h>
#include <math.h>

#define NSEQ   1024
#define HEADS  8
#define DHEAD  64
#define SCALE  0.125f

typedef unsigned int u32;
typedef unsigned short u16;
typedef short short8 __attribute__((ext_vector_type(8)));   // 8 bf16 (4 VGPRs)
typedef float f32x4  __attribute__((ext_vector_type(4)));
typedef float f32x16 __attribute__((ext_vector_type(16)));

__device__ __forceinline__ u16 f2bf(float f) {
    u32 u = __float_as_uint(f);
    return (u16)((u + 0x7fffu + ((u >> 16) & 1u)) >> 16);   // RNE
}
__device__ __forceinline__ u32 pk2(float lo, float hi) {
    return (u32)f2bf(lo) | ((u32)f2bf(hi) << 16);
}
__device__ __forceinline__ f32x4 mfma16(short8 a, short8 b, f32x4 c) {
    return __builtin_amdgcn_mfma_f32_16x16x32_bf16(a, b, c, 0, 0, 0);
}
__device__ __forceinline__ f32x16 mfma32(short8 a, short8 b, f32x16 c) {
    return __builtin_amdgcn_mfma_f32_32x32x16_bf16(a, b, c, 0, 0, 0);
}

// ---------------------------------------------------------------------------
// fp32 -> bf16 straight convert (x)
// ---------------------------------------------------------------------------
__global__ __launch_bounds__(256) void conv_bf16(const float* __restrict__ in,
                                                 u16* __restrict__ out, int n) {
    int i = (blockIdx.x * 256 + threadIdx.x) * 8;
    if (i >= n) return;
    float4 a = *(const float4*)&in[i];
    float4 b = *(const float4*)&in[i + 4];
    short8 v;
    v[0] = (short)f2bf(a.x); v[1] = (short)f2bf(a.y);
    v[2] = (short)f2bf(a.z); v[3] = (short)f2bf(a.w);
    v[4] = (short)f2bf(b.x); v[5] = (short)f2bf(b.y);
    v[6] = (short)f2bf(b.z); v[7] = (short)f2bf(b.w);
    *(short8*)&out[i] = v;
}

// ---------------------------------------------------------------------------
// fp32 [K][N] -> bf16 [N][K] transpose-convert (weights)
// ---------------------------------------------------------------------------
__global__ __launch_bounds__(256) void transpose_bf16(const float* __restrict__ in,
                                                      u16* __restrict__ out,
                                                      int K, int N) {
    __shared__ float T[64][65];
    const int n0 = blockIdx.x * 64, k0 = blockIdx.y * 64;
    const int t = threadIdx.x;
    #pragma unroll
    for (int rep = 0; rep < 4; ++rep) {
        int r = rep * 16 + (t >> 4), c = (t & 15) * 4;
        float4 v = *(const float4*)&in[(size_t)(k0 + r) * N + n0 + c];
        T[r][c + 0] = v.x; T[r][c + 1] = v.y; T[r][c + 2] = v.z; T[r][c + 3] = v.w;
    }
    __syncthreads();
    const int nl = t >> 2, kb = (t & 3) * 16;
    short8 s0, s1;
    #pragma unroll
    for (int e = 0; e < 8; ++e) s0[e] = (short)f2bf(T[kb + e][nl]);
    #pragma unroll
    for (int e = 0; e < 8; ++e) s1[e] = (short)f2bf(T[kb + 8 + e][nl]);
    *(short8*)&out[(size_t)(n0 + nl) * K + k0 + kb] = s0;
    *(short8*)&out[(size_t)(n0 + nl) * K + k0 + kb + 8] = s1;
}

// ---------------------------------------------------------------------------
// GEMM qkv: C = x_bf[4096,512] @ w (wT[1536][512] bf16). BM=128 x BN=64 tile
// -> grid 24x32 = 768 blocks (3/CU exact). 4 waves 2x2; wave tile 64x32
// (q/k path) or swapped for the v path (writes vT[b,h,d,n] = C^T directly).
// ---------------------------------------------------------------------------
__global__ __launch_bounds__(256) void gemm_qkv_mfma(const u16* __restrict__ xb,
                                                     const u16* __restrict__ wT,
                                                     u16* __restrict__ qb,
                                                     u16* __restrict__ kb,
                                                     u16* __restrict__ vT) {
    __shared__ u16 As[128][40];
    __shared__ u16 Bs[64][40];
    const int t = threadIdx.x, lane = t & 63, w = t >> 6;
    const int wm = w >> 1, wn = w & 1;
    const int l15 = lane & 15, l4 = lane >> 4;
    const int j0 = blockIdx.x * 64, i0 = blockIdx.y * 128;
    const int which = j0 / 512;           // 0=q 1=k 2=v (uniform per block)
    const int b = i0 >> 10;

    f32x4 acc[8];
    #pragma unroll
    for (int i = 0; i < 8; ++i) acc[i] = (f32x4){0.f, 0.f, 0.f, 0.f};

    short8 ra[2], rbv;
    #pragma unroll
    for (int rep = 0; rep < 2; ++rep) {
        int row = rep * 64 + (t >> 2), c8 = (t & 3) * 8;
        ra[rep] = *(const short8*)&xb[(size_t)(i0 + row) * 512 + c8];
    }
    {
        int row = t >> 2, c8 = (t & 3) * 8;
        rbv = *(const short8*)&wT[(size_t)(j0 + row) * 512 + c8];
    }

    for (int kt = 0; kt < 16; ++kt) {
        __syncthreads();
        #pragma unroll
        for (int rep = 0; rep < 2; ++rep) {
            int row = rep * 64 + (t >> 2), c8 = (t & 3) * 8;
            *(short8*)&As[row][c8] = ra[rep];
        }
        {
            int row = t >> 2, c8 = (t & 3) * 8;
            *(short8*)&Bs[row][c8] = rbv;
        }
        __syncthreads();
        if (kt < 15) {
            int k0 = (kt + 1) * 32;
            #pragma unroll
            for (int rep = 0; rep < 2; ++rep) {
                int row = rep * 64 + (t >> 2), c8 = (t & 3) * 8;
                ra[rep] = *(const short8*)&xb[(size_t)(i0 + row) * 512 + k0 + c8];
            }
            int row = t >> 2, c8 = (t & 3) * 8;
            rbv = *(const short8*)&wT[(size_t)(j0 + row) * 512 + k0 + c8];
        }
        if (which < 2) {
            short8 af[4], bf[2];
            #pragma unroll
            for (int m = 0; m < 4; ++m)
                af[m] = *(const short8*)&As[wm * 64 + m * 16 + l15][l4 * 8];
            #pragma unroll
            for (int n = 0; n < 2; ++n)
                bf[n] = *(const short8*)&Bs[wn * 32 + n * 16 + l15][l4 * 8];
            #pragma unroll
            for (int m = 0; m < 4; ++m)
                #pragma unroll
                for (int n = 0; n < 2; ++n)
                    acc[m * 2 + n] = mfma16(af[m], bf[n], acc[m * 2 + n]);
        } else {
            short8 af[2], bf[4];
            #pragma unroll
            for (int mj = 0; mj < 2; ++mj)
                af[mj] = *(const short8*)&Bs[wn * 32 + mj * 16 + l15][l4 * 8];
            #pragma unroll
            for (int ni = 0; ni < 4; ++ni)
                bf[ni] = *(const short8*)&As[wm * 64 + ni * 16 + l15][l4 * 8];
            #pragma unroll
            for (int mj = 0; mj < 2; ++mj)
                #pragma unroll
                for (int ni = 0; ni < 4; ++ni)
                    acc[mj * 4 + ni] = mfma16(af[mj], bf[ni], acc[mj * 4 + ni]);
        }
    }

    if (which < 2) {
        u16* dst = (which == 0) ? qb : kb;
        const int h = (j0 & 511) >> 6;
        #pragma unroll
        for (int m = 0; m < 4; ++m)
            #pragma unroll
            for (int n = 0; n < 2; ++n) {
                int d = wn * 32 + n * 16 + l15;
                #pragma unroll
                for (int r = 0; r < 4; ++r) {
                    int tok = i0 + wm * 64 + m * 16 + l4 * 4 + r;
                    dst[(((size_t)(b * HEADS + h)) * NSEQ + (tok & 1023)) * DHEAD + d] =
                        f2bf(acc[m * 2 + n][r]);
                }
            }
    } else {
        const int h = (j0 - 1024) >> 6;
        #pragma unroll
        for (int mj = 0; mj < 2; ++mj)
            #pragma unroll
            for (int ni = 0; ni < 4; ++ni) {
                int tok = i0 + wm * 64 + ni * 16 + l15;
                #pragma unroll
                for (int r = 0; r < 4; ++r) {
                    int d = wn * 32 + mj * 16 + l4 * 4 + r;
                    vT[(((size_t)(b * HEADS + h)) * DHEAD + d) * NSEQ + (tok & 1023)] =
                        f2bf(acc[mj * 4 + ni][r]);
                }
            }
    }
}

// ---------------------------------------------------------------------------
// Flash attention, swapped-QK^T form, KVBLK=64.  Block = (b,h) x 128 i-rows,
// 4 waves, each owns 32 i-cols of S^T.  16 j-iterations of 64 keys.
// S^T = mfma32(K,Q); softmax in-register; P via pack+shfl_xor(32);
// O += mfma32(P, V^T).  spd bounced through LDS (stride-65 fp32,
// conflict-free reads).
// ---------------------------------------------------------------------------
__global__ __launch_bounds__(256) void attn_mfma(const u16* __restrict__ qb,
                                                 const u16* __restrict__ kb,
                                                 const u16* __restrict__ vT,
                                                 const float* __restrict__ spd,
                                                 const float* __restrict__ head_keep,
                                                 u16* __restrict__ ab) {
    __shared__ u16 Qs[128][72];
    __shared__ u16 Ks[64][72];
    __shared__ u16 Vs[64][72];
    __shared__ float Ss[128][65];

    const int t = threadIdx.x, lane = t & 63, w = t >> 6;
    const int hi = lane >> 5, li = lane & 31;
    const int bh = blockIdx.y, b = bh >> 3, h = bh & 7;
    const int i0 = blockIdx.x * 128;

    const u16* qh = qb + (size_t)bh * NSEQ * DHEAD;
    const u16* kh = kb + (size_t)bh * NSEQ * DHEAD;
    const u16* vh = vT + (size_t)bh * DHEAD * NSEQ;
    const float* sp = spd + (size_t)bh * NSEQ * NSEQ;

    // Q tile [128][64]
    #pragma unroll
    for (int rep = 0; rep < 4; ++rep) {
        int row = rep * 32 + (t >> 3), c8 = (t & 7) * 8;
        *(short8*)&Qs[row][c8] = *(const short8*)&qh[(size_t)(i0 + row) * DHEAD + c8];
    }

    float m_s = -1e30f, l_s = 0.f;
    f32x16 o0 = {}, o1 = {};
    #pragma unroll
    for (int r = 0; r < 16; ++r) { o0[r] = 0.f; o1[r] = 0.f; }

    // prologue loads (jt = 0): K 64x64, V^T 64x64, spd 128x64
    short8 rk[2], rv[2];
    float4 rs[8];
    {
        int row = t >> 3, c8 = (t & 7) * 8;
        #pragma unroll
        for (int rep = 0; rep < 2; ++rep) {
            rk[rep] = *(const short8*)&kh[(size_t)(rep * 32 + row) * DHEAD + c8];
            rv[rep] = *(const short8*)&vh[(size_t)(rep * 32 + row) * NSEQ + c8];
        }
        #pragma unroll
        for (int rep = 0; rep < 8; ++rep) {
            int rrow = rep * 16 + (t >> 4), c = (t & 15) * 4;
            rs[rep] = *(const float4*)&sp[(size_t)(i0 + rrow) * NSEQ + c];
        }
    }

    for (int jt = 0; jt < 16; ++jt) {
        __syncthreads();   // protect previous iteration's LDS reads (and Q at jt=0)
        {
            int row = t >> 3, c8 = (t & 7) * 8;
            #pragma unroll
            for (int rep = 0; rep < 2; ++rep) {
                *(short8*)&Ks[rep * 32 + row][c8] = rk[rep];
                *(short8*)&Vs[rep * 32 + row][c8] = rv[rep];
            }
            #pragma unroll
            for (int rep = 0; rep < 8; ++rep) {
                int rrow = rep * 16 + (t >> 4), c = (t & 15) * 4;
                Ss[rrow][c + 0] = rs[rep].x; Ss[rrow][c + 1] = rs[rep].y;
                Ss[rrow][c + 2] = rs[rep].z; Ss[rrow][c + 3] = rs[rep].w;
            }
        }
        __syncthreads();
        if (jt < 15) {   // prefetch next 64-key tile
            int j0n = (jt + 1) * 64;
            int row = t >> 3, c8 = (t & 7) * 8;
            #pragma unroll
            for (int rep = 0; rep < 2; ++rep) {
                rk[rep] = *(const short8*)&kh[(size_t)(j0n + rep * 32 + row) * DHEAD + c8];
                rv[rep] = *(const short8*)&vh[(size_t)(rep * 32 + row) * NSEQ + j0n + c8];
            }
            #pragma unroll
            for (int rep = 0; rep < 8; ++rep) {
                int rrow = rep * 16 + (t >> 4), c = (t & 15) * 4;
                rs[rep] = *(const float4*)&sp[(size_t)(i0 + rrow) * NSEQ + j0n + c];
            }
        }

        // S^T[key][i] = sum_d K[key][d] Q[i][d]; 2 key-groups of 32
        f32x16 s2[2];
        #pragma unroll
        for (int kg = 0; kg < 2; ++kg) {
            #pragma unroll
            for (int r = 0; r < 16; ++r) s2[kg][r] = 0.f;
            #pragma unroll
            for (int ds = 0; ds < 4; ++ds) {
                short8 ak = *(const short8*)&Ks[kg * 32 + li][ds * 16 + hi * 8];
                short8 bq = *(const short8*)&Qs[w * 32 + li][ds * 16 + hi * 8];
                s2[kg] = mfma32(ak, bq, s2[kg]);
            }
        }

        // softmax: lane li owns i-col w*32+li; 32 of 64 keys per lane
        float p[32], pmax = -1e30f;
        #pragma unroll
        for (int kg = 0; kg < 2; ++kg)
            #pragma unroll
            for (int r = 0; r < 16; ++r) {
                int key = kg * 32 + (r & 3) + 8 * (r >> 2) + 4 * hi;
                float v = s2[kg][r] * SCALE + Ss[w * 32 + li][key];
                p[kg * 16 + r] = v;
                pmax = fmaxf(pmax, v);
            }
        pmax = fmaxf(pmax, __shfl_xor(pmax, 32));
        float mnew = fmaxf(m_s, pmax);
        float fac = __expf(m_s - mnew);
        m_s = mnew;
        float rsum = 0.f;
        #pragma unroll
        for (int r = 0; r < 32; ++r) { p[r] = __expf(p[r] - mnew); rsum += p[r]; }
        rsum += __shfl_xor(rsum, 32);
        l_s = l_s * fac + rsum;

        // rescale O rows
        #pragma unroll
        for (int r = 0; r < 16; ++r) {
            int ip = (r & 3) + 8 * (r >> 2) + 4 * hi;
            float fr = __shfl(fac, ip);
            o0[r] *= fr; o1[r] *= fr;
        }

        // P fragments: A[i=li][key], key = ks*16 + hi*8 + e, ks = 0..3
        short8 pf[4];
        #pragma unroll
        for (int ks = 0; ks < 4; ++ks) {
            int rb = (ks >> 1) * 16 + (ks & 1) * 8;
            u32 a0 = pk2(p[rb + 0], p[rb + 1]);
            u32 a1 = pk2(p[rb + 2], p[rb + 3]);
            u32 a2 = pk2(p[rb + 4], p[rb + 5]);
            u32 a3 = pk2(p[rb + 6], p[rb + 7]);
            u32 x0 = (u32)__shfl_xor((int)a0, 32);
            u32 x1 = (u32)__shfl_xor((int)a1, 32);
            u32 x2 = (u32)__shfl_xor((int)a2, 32);
            u32 x3 = (u32)__shfl_xor((int)a3, 32);
            union { u32 u[4]; short8 v; } c4;
            c4.u[0] = hi ? x2 : a0;
            c4.u[1] = hi ? x3 : a1;
            c4.u[2] = hi ? a2 : x0;
            c4.u[3] = hi ? a3 : x1;
            pf[ks] = c4.v;
        }

        // O += P * V   (B-frag: V^T[d][key])
        #pragma unroll
        for (int ks = 0; ks < 4; ++ks) {
            short8 v0f = *(const short8*)&Vs[li][ks * 16 + hi * 8];
            short8 v1f = *(const short8*)&Vs[32 + li][ks * 16 + hi * 8];
            o0 = mfma32(pf[ks], v0f, o0);
            o1 = mfma32(pf[ks], v1f, o1);
        }
    }

    // epilogue
    float ksum = 0.f;
    #pragma unroll
    for (int i = 0; i < HEADS; ++i) ksum += head_keep[i];
    const float hscale = head_keep[h] * (float)HEADS / ksum;
    const float inv = hscale / l_s;
    #pragma unroll
    for (int r = 0; r < 16; ++r) {
        int ip = (r & 3) + 8 * (r >> 2) + 4 * hi;
        float invr = __shfl(inv, ip);
        int tok = i0 + w * 32 + ip;
        size_t base = ((size_t)(b * NSEQ) + tok) * 512 + h * DHEAD;
        ab[base + li]      = f2bf(o0[r] * invr);
        ab[base + 32 + li] = f2bf(o1[r] * invr);
    }
}

// ---------------------------------------------------------------------------
// GEMM out: out[4096,512] = abuf_bf[4096,512] @ woutT + bias.  BM=128 x BN=64
// -> grid 8x32 = 256 blocks (1/CU exact).
// ---------------------------------------------------------------------------
__global__ __launch_bounds__(256) void gemm_out_mfma(const u16* __restrict__ abuf,
                                                     const u16* __restrict__ wT,
                                                     const float* __restrict__ bias,
                                                     float* __restrict__ out) {
    __shared__ u16 As[128][40];
    __shared__ u16 Bs[64][40];
    const int t = threadIdx.x, lane = t & 63, w = t >> 6;
    const int wm = w >> 1, wn = w & 1;
    const int l15 = lane & 15, l4 = lane >> 4;
    const int j0 = blockIdx.x * 64, i0 = blockIdx.y * 128;

    f32x4 acc[4][2];
    #pragma unroll
    for (int m = 0; m < 4; ++m)
        #pragma unroll
        for (int n = 0; n < 2; ++n) acc[m][n] = (f32x4){0.f, 0.f, 0.f, 0.f};

    short8 ra[2], rbv;
    #pragma unroll
    for (int rep = 0; rep < 2; ++rep) {
        int row = rep * 64 + (t >> 2), c8 = (t & 3) * 8;
        ra[rep] = *(const short8*)&abuf[(size_t)(i0 + row) * 512 + c8];
    }
    {
        int row = t >> 2, c8 = (t & 3) * 8;
        rbv = *(const short8*)&wT[(size_t)(j0 + row) * 512 + c8];
    }

    for (int kt = 0; kt < 16; ++kt) {
        __syncthreads();
        #pragma unroll
        for (int rep = 0; rep < 2; ++rep) {
            int row = rep * 64 + (t >> 2), c8 = (t & 3) * 8;
            *(short8*)&As[row][c8] = ra[rep];
        }
        {
            int row = t >> 2, c8 = (t & 3) * 8;
            *(short8*)&Bs[row][c8] = rbv;
        }
        __syncthreads();
        if (kt < 15) {
            int k0 = (kt + 1) * 32;
            #pragma unroll
            for (int rep = 0; rep < 2; ++rep) {
                int row = rep * 64 + (t >> 2), c8 = (t & 3) * 8;
                ra[rep] = *(const short8*)&abuf[(size_t)(i0 + row) * 512 + k0 + c8];
            }
            int row = t >> 2, c8 = (t & 3) * 8;
            rbv = *(const short8*)&wT[(size_t)(j0 + row) * 512 + k0 + c8];
        }
        short8 af[4], bf[2];
        #pragma unroll
        for (int m = 0; m < 4; ++m)
            af[m] = *(const short8*)&As[wm * 64 + m * 16 + l15][l4 * 8];
        #pragma unroll
        for (int n = 0; n < 2; ++n)
            bf[n] = *(const short8*)&Bs[wn * 32 + n * 16 + l15][l4 * 8];
        #pragma unroll
        for (int m = 0; m < 4; ++m)
            #pragma unroll
            for (int n = 0; n < 2; ++n)
                acc[m][n] = mfma16(af[m], bf[n], acc[m][n]);
    }

    #pragma unroll
    for (int m = 0; m < 4; ++m)
        #pragma unroll
        for (int n = 0; n < 2; ++n) {
            int col = j0 + wn * 32 + n * 16 + l15;
            float bb = bias[col];
            #pragma unroll
            for (int r = 0; r < 4; ++r) {
                int row = i0 + wm * 64 + m * 16 + l4 * 4 + r;
                out[(size_t)row * 512 + col] = acc[m][n][r] + bb;
            }
        }
}

extern "C" void kernel_launch(void* const* d_in, const int* in_sizes, int n_in,
                              void* d_out, int out_size, void* d_ws, size_t ws_size,
                              hipStream_t stream) {
    const float* x         = (const float*)d_in[0];
    const float* spd       = (const float*)d_in[1];
    const float* head_keep = (const float*)d_in[2];
    const float* w_qkv     = (const float*)d_in[3];
    const float* w_out     = (const float*)d_in[4];
    const float* b_out     = (const float*)d_in[5];
    float* out = (float*)d_out;

    char* ws = (char*)d_ws;
    u16* x_bf   = (u16*)(ws);                       // 4096*512
    u16* wqkvT  = (u16*)(ws + (4u << 20));          // 1536*512
    u16* woutT  = (u16*)(ws + (4u << 20) + 1572864);// 512*512
    u16* qb     = (u16*)(ws + (6u << 20));          // 32*1024*64
    u16* kb     = (u16*)(ws + (10u << 20));
    u16* vT     = (u16*)(ws + (14u << 20));
    u16* ab     = (u16*)(ws + (18u << 20));         // 4096*512

    conv_bf16<<<1024, 256, 0, stream>>>(x, x_bf, 4096 * 512);
    transpose_bf16<<<dim3(24, 8), 256, 0, stream>>>(w_qkv, wqkvT, 512, 1536);
    transpose_bf16<<<dim3(8, 8), 256, 0, stream>>>(w_out, woutT, 512, 512);
    gemm_qkv_mfma<<<dim3(24, 32), 256, 0, stream>>>(x_bf, wqkvT, qb, kb, vT);
    attn_mfma<<<dim3(8, 32), 256, 0, stream>>>(qb, kb, vT, spd, head_keep, ab);
    gemm_out_mfma<<<dim3(8, 32), 256, 0, stream>>>(ab, woutT, b_out, out);
}

// Round 7
// 67.602 us; speedup vs baseline: 4.0527x; 1.2009x over previous
//
#include <hip/hip_runtime.h>
#include <math.h>

#define NSEQ   1024
#define HEADS  8
#define DHEAD  64
#define SCALE  0.125f
#define LOG2E  1.4426950408889634f

typedef unsigned int u32;
typedef unsigned short u16;
typedef short short8 __attribute__((ext_vector_type(8)));   // 8 bf16 (4 VGPRs)
typedef __bf16 bf16x2 __attribute__((ext_vector_type(2)));
typedef __bf16 bf16x8 __attribute__((ext_vector_type(8)));
typedef float f32x4  __attribute__((ext_vector_type(4)));
typedef float f32x16 __attribute__((ext_vector_type(16)));

// native casts -> compiler emits v_cvt_pk_bf16_f32 (RNE), ~1 op per 2 floats
__device__ __forceinline__ u16 f2bf(float f) {
    __bf16 h = (__bf16)f;
    return __builtin_bit_cast(u16, h);
}
__device__ __forceinline__ u32 pk2(float lo, float hi) {
    bf16x2 v; v[0] = (__bf16)lo; v[1] = (__bf16)hi;
    return __builtin_bit_cast(u32, v);
}
// NO inline-asm here: raw v_exp_f32 in asm has a TRANS-pipe read-after-write
// hazard the compiler can't see (caused nondeterministic replay corruption in
// R6). exp2f() lowers to a correctly-scheduled v_exp_f32 sequence.
__device__ __forceinline__ float exp2_fast(float x) {
#if __has_builtin(__builtin_amdgcn_exp2f)
    return __builtin_amdgcn_exp2f(x);
#else
    return exp2f(x);
#endif
}
__device__ __forceinline__ f32x4 mfma16(short8 a, short8 b, f32x4 c) {
    return __builtin_amdgcn_mfma_f32_16x16x32_bf16(a, b, c, 0, 0, 0);
}
__device__ __forceinline__ f32x16 mfma32(short8 a, short8 b, f32x16 c) {
    return __builtin_amdgcn_mfma_f32_32x32x16_bf16(a, b, c, 0, 0, 0);
}

// ---------------------------------------------------------------------------
// prep: one kernel for x->bf16 convert + both weight transpose-converts.
// blocks [0,1024): conv x; [1024,1216): w_qkv^T; [1216,1280): w_out^T.
// ---------------------------------------------------------------------------
__global__ __launch_bounds__(256) void prep(const float* __restrict__ x,
                                            const float* __restrict__ wqkv,
                                            const float* __restrict__ wout,
                                            u16* __restrict__ x_bf,
                                            u16* __restrict__ wqkvT,
                                            u16* __restrict__ woutT) {
    __shared__ float T[64][65];
    const int t = threadIdx.x;
    const int bb = blockIdx.x;
    if (bb < 1024) {
        int i = (bb * 256 + t) * 8;
        float4 a = *(const float4*)&x[i];
        float4 b = *(const float4*)&x[i + 4];
        bf16x8 v;
        v[0] = (__bf16)a.x; v[1] = (__bf16)a.y; v[2] = (__bf16)a.z; v[3] = (__bf16)a.w;
        v[4] = (__bf16)b.x; v[5] = (__bf16)b.y; v[6] = (__bf16)b.z; v[7] = (__bf16)b.w;
        *(short8*)&x_bf[i] = __builtin_bit_cast(short8, v);
        return;
    }
    const float* in; u16* outp; int K, N, n0, k0;
    if (bb < 1216) {
        int bid = bb - 1024;
        in = wqkv; outp = wqkvT; K = 512; N = 1536;
        n0 = (bid % 24) * 64; k0 = (bid / 24) * 64;
    } else {
        int bid = bb - 1216;
        in = wout; outp = woutT; K = 512; N = 512;
        n0 = (bid % 8) * 64; k0 = (bid / 8) * 64;
    }
    #pragma unroll
    for (int rep = 0; rep < 4; ++rep) {
        int r = rep * 16 + (t >> 4), c = (t & 15) * 4;
        float4 v = *(const float4*)&in[(size_t)(k0 + r) * N + n0 + c];
        T[r][c + 0] = v.x; T[r][c + 1] = v.y; T[r][c + 2] = v.z; T[r][c + 3] = v.w;
    }
    __syncthreads();
    const int nl = t >> 2, kb = (t & 3) * 16;
    bf16x8 s0, s1;
    #pragma unroll
    for (int e = 0; e < 8; ++e) s0[e] = (__bf16)T[kb + e][nl];
    #pragma unroll
    for (int e = 0; e < 8; ++e) s1[e] = (__bf16)T[kb + 8 + e][nl];
    *(short8*)&outp[(size_t)(n0 + nl) * K + k0 + kb]     = __builtin_bit_cast(short8, s0);
    *(short8*)&outp[(size_t)(n0 + nl) * K + k0 + kb + 8] = __builtin_bit_cast(short8, s1);
}

// ---------------------------------------------------------------------------
// GEMM qkv: C = x_bf[4096,512] @ w (wT[1536][512] bf16). BM=128 x BN=64 tile
// -> grid 24x32 = 768 blocks (3/CU exact). 4 waves 2x2; wave tile 64x32
// (q/k path) or swapped for the v path (writes vT[b,h,d,n] = C^T directly).
// ---------------------------------------------------------------------------
__global__ __launch_bounds__(256) void gemm_qkv_mfma(const u16* __restrict__ xb,
                                                     const u16* __restrict__ wT,
                                                     u16* __restrict__ qb,
                                                     u16* __restrict__ kb,
                                                     u16* __restrict__ vT) {
    __shared__ u16 As[128][40];
    __shared__ u16 Bs[64][40];
    const int t = threadIdx.x, lane = t & 63, w = t >> 6;
    const int wm = w >> 1, wn = w & 1;
    const int l15 = lane & 15, l4 = lane >> 4;
    const int j0 = blockIdx.x * 64, i0 = blockIdx.y * 128;
    const int which = j0 / 512;           // 0=q 1=k 2=v (uniform per block)
    const int b = i0 >> 10;

    f32x4 acc[8];
    #pragma unroll
    for (int i = 0; i < 8; ++i) acc[i] = (f32x4){0.f, 0.f, 0.f, 0.f};

    short8 ra[2], rbv;
    #pragma unroll
    for (int rep = 0; rep < 2; ++rep) {
        int row = rep * 64 + (t >> 2), c8 = (t & 3) * 8;
        ra[rep] = *(const short8*)&xb[(size_t)(i0 + row) * 512 + c8];
    }
    {
        int row = t >> 2, c8 = (t & 3) * 8;
        rbv = *(const short8*)&wT[(size_t)(j0 + row) * 512 + c8];
    }

    for (int kt = 0; kt < 16; ++kt) {
        __syncthreads();
        #pragma unroll
        for (int rep = 0; rep < 2; ++rep) {
            int row = rep * 64 + (t >> 2), c8 = (t & 3) * 8;
            *(short8*)&As[row][c8] = ra[rep];
        }
        {
            int row = t >> 2, c8 = (t & 3) * 8;
            *(short8*)&Bs[row][c8] = rbv;
        }
        __syncthreads();
        if (kt < 15) {
            int k0 = (kt + 1) * 32;
            #pragma unroll
            for (int rep = 0; rep < 2; ++rep) {
                int row = rep * 64 + (t >> 2), c8 = (t & 3) * 8;
                ra[rep] = *(const short8*)&xb[(size_t)(i0 + row) * 512 + k0 + c8];
            }
            int row = t >> 2, c8 = (t & 3) * 8;
            rbv = *(const short8*)&wT[(size_t)(j0 + row) * 512 + k0 + c8];
        }
        if (which < 2) {
            short8 af[4], bf[2];
            #pragma unroll
            for (int m = 0; m < 4; ++m)
                af[m] = *(const short8*)&As[wm * 64 + m * 16 + l15][l4 * 8];
            #pragma unroll
            for (int n = 0; n < 2; ++n)
                bf[n] = *(const short8*)&Bs[wn * 32 + n * 16 + l15][l4 * 8];
            #pragma unroll
            for (int m = 0; m < 4; ++m)
                #pragma unroll
                for (int n = 0; n < 2; ++n)
                    acc[m * 2 + n] = mfma16(af[m], bf[n], acc[m * 2 + n]);
        } else {
            short8 af[2], bf[4];
            #pragma unroll
            for (int mj = 0; mj < 2; ++mj)
                af[mj] = *(const short8*)&Bs[wn * 32 + mj * 16 + l15][l4 * 8];
            #pragma unroll
            for (int ni = 0; ni < 4; ++ni)
                bf[ni] = *(const short8*)&As[wm * 64 + ni * 16 + l15][l4 * 8];
            #pragma unroll
            for (int mj = 0; mj < 2; ++mj)
                #pragma unroll
                for (int ni = 0; ni < 4; ++ni)
                    acc[mj * 4 + ni] = mfma16(af[mj], bf[ni], acc[mj * 4 + ni]);
        }
    }

    if (which < 2) {
        u16* dst = (which == 0) ? qb : kb;
        const int h = (j0 & 511) >> 6;
        #pragma unroll
        for (int m = 0; m < 4; ++m)
            #pragma unroll
            for (int n = 0; n < 2; ++n) {
                int d = wn * 32 + n * 16 + l15;
                #pragma unroll
                for (int r = 0; r < 4; ++r) {
                    int tok = i0 + wm * 64 + m * 16 + l4 * 4 + r;
                    dst[(((size_t)(b * HEADS + h)) * NSEQ + (tok & 1023)) * DHEAD + d] =
                        f2bf(acc[m * 2 + n][r]);
                }
            }
    } else {
        const int h = (j0 - 1024) >> 6;
        #pragma unroll
        for (int mj = 0; mj < 2; ++mj)
            #pragma unroll
            for (int ni = 0; ni < 4; ++ni) {
                int tok = i0 + wm * 64 + ni * 16 + l15;
                #pragma unroll
                for (int r = 0; r < 4; ++r) {
                    int d = wn * 32 + mj * 16 + l4 * 4 + r;
                    vT[(((size_t)(b * HEADS + h)) * DHEAD + d) * NSEQ + (tok & 1023)] =
                        f2bf(acc[mj * 4 + ni][r]);
                }
            }
    }
}

// ---------------------------------------------------------------------------
// Flash attention, swapped-QK^T, KVBLK=64, log2-domain softmax + defer-max.
// Block = (b,h) x 128 i-rows, 4 waves, each owns 32 i-cols of S^T.
// ---------------------------------------------------------------------------
__global__ __launch_bounds__(256) void attn_mfma(const u16* __restrict__ qb,
                                                 const u16* __restrict__ kb,
                                                 const u16* __restrict__ vT,
                                                 const float* __restrict__ spd,
                                                 const float* __restrict__ head_keep,
                                                 u16* __restrict__ ab) {
    __shared__ u16 Qs[128][72];
    __shared__ u16 Ks[64][72];
    __shared__ u16 Vs[64][72];
    __shared__ float Ss[128][65];

    const int t = threadIdx.x, lane = t & 63, w = t >> 6;
    const int hi = lane >> 5, li = lane & 31;
    const int bh = blockIdx.y, b = bh >> 3, h = bh & 7;
    const int i0 = blockIdx.x * 128;

    const u16* qh = qb + (size_t)bh * NSEQ * DHEAD;
    const u16* kh = kb + (size_t)bh * NSEQ * DHEAD;
    const u16* vh = vT + (size_t)bh * DHEAD * NSEQ;
    const float* sp = spd + (size_t)bh * NSEQ * NSEQ;

    // Q tile [128][64]
    #pragma unroll
    for (int rep = 0; rep < 4; ++rep) {
        int row = rep * 32 + (t >> 3), c8 = (t & 7) * 8;
        *(short8*)&Qs[row][c8] = *(const short8*)&qh[(size_t)(i0 + row) * DHEAD + c8];
    }

    float m_s = -1e30f, l_s = 0.f;
    f32x16 o0 = {}, o1 = {};
    #pragma unroll
    for (int r = 0; r < 16; ++r) { o0[r] = 0.f; o1[r] = 0.f; }

    // prologue loads (jt = 0): K 64x64, V^T 64x64, spd 128x64
    short8 rk[2], rv[2];
    float4 rs[8];
    {
        int row = t >> 3, c8 = (t & 7) * 8;
        #pragma unroll
        for (int rep = 0; rep < 2; ++rep) {
            rk[rep] = *(const short8*)&kh[(size_t)(rep * 32 + row) * DHEAD + c8];
            rv[rep] = *(const short8*)&vh[(size_t)(rep * 32 + row) * NSEQ + c8];
        }
        #pragma unroll
        for (int rep = 0; rep < 8; ++rep) {
            int rrow = rep * 16 + (t >> 4), c = (t & 15) * 4;
            rs[rep] = *(const float4*)&sp[(size_t)(i0 + rrow) * NSEQ + c];
        }
    }

    for (int jt = 0; jt < 16; ++jt) {
        __syncthreads();   // protect previous iteration's LDS reads (and Q at jt=0)
        {
            int row = t >> 3, c8 = (t & 7) * 8;
            #pragma unroll
            for (int rep = 0; rep < 2; ++rep) {
                *(short8*)&Ks[rep * 32 + row][c8] = rk[rep];
                *(short8*)&Vs[rep * 32 + row][c8] = rv[rep];
            }
            #pragma unroll
            for (int rep = 0; rep < 8; ++rep) {   // pre-scale by log2e at staging
                int rrow = rep * 16 + (t >> 4), c = (t & 15) * 4;
                Ss[rrow][c + 0] = rs[rep].x * LOG2E;
                Ss[rrow][c + 1] = rs[rep].y * LOG2E;
                Ss[rrow][c + 2] = rs[rep].z * LOG2E;
                Ss[rrow][c + 3] = rs[rep].w * LOG2E;
            }
        }
        __syncthreads();
        if (jt < 15) {   // prefetch next 64-key tile
            int j0n = (jt + 1) * 64;
            int row = t >> 3, c8 = (t & 7) * 8;
            #pragma unroll
            for (int rep = 0; rep < 2; ++rep) {
                rk[rep] = *(const short8*)&kh[(size_t)(j0n + rep * 32 + row) * DHEAD + c8];
                rv[rep] = *(const short8*)&vh[(size_t)(rep * 32 + row) * NSEQ + j0n + c8];
            }
            #pragma unroll
            for (int rep = 0; rep < 8; ++rep) {
                int rrow = rep * 16 + (t >> 4), c = (t & 15) * 4;
                rs[rep] = *(const float4*)&sp[(size_t)(i0 + rrow) * NSEQ + j0n + c];
            }
        }

        // S^T[key][i] = sum_d K[key][d] Q[i][d]; 2 key-groups of 32
        f32x16 s2[2];
        #pragma unroll
        for (int kg = 0; kg < 2; ++kg) {
            #pragma unroll
            for (int r = 0; r < 16; ++r) s2[kg][r] = 0.f;
            #pragma unroll
            for (int ds = 0; ds < 4; ++ds) {
                short8 ak = *(const short8*)&Ks[kg * 32 + li][ds * 16 + hi * 8];
                short8 bq = *(const short8*)&Qs[w * 32 + li][ds * 16 + hi * 8];
                s2[kg] = mfma32(ak, bq, s2[kg]);
            }
        }

        // log2-domain scores: p2 = s*scale*log2e + spd*log2e
        float p2[32];
        #pragma unroll
        for (int kg = 0; kg < 2; ++kg)
            #pragma unroll
            for (int r = 0; r < 16; ++r) {
                int key = kg * 32 + (r & 3) + 8 * (r >> 2) + 4 * hi;
                p2[kg * 16 + r] = fmaf(s2[kg][r], SCALE * LOG2E, Ss[w * 32 + li][key]);
            }
        // tree max
        float m16[16];
        #pragma unroll
        for (int r = 0; r < 16; ++r) m16[r] = fmaxf(p2[r], p2[r + 16]);
        float m8v[8];
        #pragma unroll
        for (int r = 0; r < 8; ++r) m8v[r] = fmaxf(m16[r], m16[r + 8]);
        float m4v[4];
        #pragma unroll
        for (int r = 0; r < 4; ++r) m4v[r] = fmaxf(m8v[r], m8v[r + 4]);
        float pmax = fmaxf(fmaxf(m4v[0], m4v[1]), fmaxf(m4v[2], m4v[3]));
        pmax = fmaxf(pmax, __shfl_xor(pmax, 32));

        // defer-max: only rescale when the running max grew by >12 (log2)
        if (!__all(pmax <= m_s + 12.0f)) {
            float mnew = fmaxf(m_s, pmax);
            float fac = exp2_fast(m_s - mnew);
            m_s = mnew;
            l_s *= fac;
            #pragma unroll
            for (int r = 0; r < 16; ++r) {
                int ip = (r & 3) + 8 * (r >> 2) + 4 * hi;
                float fr = __shfl(fac, ip);
                o0[r] *= fr; o1[r] *= fr;
            }
        }

        float p[32];
        float sa0 = 0.f, sa1 = 0.f, sa2 = 0.f, sa3 = 0.f;
        #pragma unroll
        for (int r = 0; r < 32; r += 4) {
            p[r + 0] = exp2_fast(p2[r + 0] - m_s); sa0 += p[r + 0];
            p[r + 1] = exp2_fast(p2[r + 1] - m_s); sa1 += p[r + 1];
            p[r + 2] = exp2_fast(p2[r + 2] - m_s); sa2 += p[r + 2];
            p[r + 3] = exp2_fast(p2[r + 3] - m_s); sa3 += p[r + 3];
        }
        float rsum = (sa0 + sa1) + (sa2 + sa3);
        rsum += __shfl_xor(rsum, 32);
        l_s += rsum;

        // P fragments: A[i=li][key], key = ks*16 + hi*8 + e, ks = 0..3
        short8 pf[4];
        #pragma unroll
        for (int ks = 0; ks < 4; ++ks) {
            int rb = (ks >> 1) * 16 + (ks & 1) * 8;
            u32 a0 = pk2(p[rb + 0], p[rb + 1]);
            u32 a1 = pk2(p[rb + 2], p[rb + 3]);
            u32 a2 = pk2(p[rb + 4], p[rb + 5]);
            u32 a3 = pk2(p[rb + 6], p[rb + 7]);
            u32 x0 = (u32)__shfl_xor((int)a0, 32);
            u32 x1 = (u32)__shfl_xor((int)a1, 32);
            u32 x2 = (u32)__shfl_xor((int)a2, 32);
            u32 x3 = (u32)__shfl_xor((int)a3, 32);
            union { u32 u[4]; short8 v; } c4;
            c4.u[0] = hi ? x2 : a0;
            c4.u[1] = hi ? x3 : a1;
            c4.u[2] = hi ? a2 : x0;
            c4.u[3] = hi ? a3 : x1;
            pf[ks] = c4.v;
        }

        // O += P * V   (B-frag: V^T[d][key])
        #pragma unroll
        for (int ks = 0; ks < 4; ++ks) {
            short8 v0f = *(const short8*)&Vs[li][ks * 16 + hi * 8];
            short8 v1f = *(const short8*)&Vs[32 + li][ks * 16 + hi * 8];
            o0 = mfma32(pf[ks], v0f, o0);
            o1 = mfma32(pf[ks], v1f, o1);
        }
    }

    // epilogue
    float ksum = 0.f;
    #pragma unroll
    for (int i = 0; i < HEADS; ++i) ksum += head_keep[i];
    const float hscale = head_keep[h] * (float)HEADS / ksum;
    const float inv = hscale / l_s;
    #pragma unroll
    for (int r = 0; r < 16; ++r) {
        int ip = (r & 3) + 8 * (r >> 2) + 4 * hi;
        float invr = __shfl(inv, ip);
        int tok = i0 + w * 32 + ip;
        size_t base = ((size_t)(b * NSEQ) + tok) * 512 + h * DHEAD;
        ab[base + li]      = f2bf(o0[r] * invr);
        ab[base + 32 + li] = f2bf(o1[r] * invr);
    }
}

// ---------------------------------------------------------------------------
// GEMM out: out[4096,512] = abuf_bf[4096,512] @ woutT + bias.  BM=64 x BN=64
// -> grid 8x64 = 512 blocks (2/CU).  4 waves 2x2, wave tile 32x32.
// ---------------------------------------------------------------------------
__global__ __launch_bounds__(256) void gemm_out_mfma(const u16* __restrict__ abuf,
                                                     const u16* __restrict__ wT,
                                                     const float* __restrict__ bias,
                                                     float* __restrict__ out) {
    __shared__ u16 As[64][40];
    __shared__ u16 Bs[64][40];
    const int t = threadIdx.x, lane = t & 63, w = t >> 6;
    const int wm = w >> 1, wn = w & 1;
    const int l15 = lane & 15, l4 = lane >> 4;
    const int j0 = blockIdx.x * 64, i0 = blockIdx.y * 64;

    f32x4 acc[2][2];
    #pragma unroll
    for (int m = 0; m < 2; ++m)
        #pragma unroll
        for (int n = 0; n < 2; ++n) acc[m][n] = (f32x4){0.f, 0.f, 0.f, 0.f};

    short8 rav, rbv;
    {
        int row = t >> 2, c8 = (t & 3) * 8;
        rav = *(const short8*)&abuf[(size_t)(i0 + row) * 512 + c8];
        rbv = *(const short8*)&wT[(size_t)(j0 + row) * 512 + c8];
    }

    for (int kt = 0; kt < 16; ++kt) {
        __syncthreads();
        {
            int row = t >> 2, c8 = (t & 3) * 8;
            *(short8*)&As[row][c8] = rav;
            *(short8*)&Bs[row][c8] = rbv;
        }
        __syncthreads();
        if (kt < 15) {
            int k0 = (kt + 1) * 32;
            int row = t >> 2, c8 = (t & 3) * 8;
            rav = *(const short8*)&abuf[(size_t)(i0 + row) * 512 + k0 + c8];
            rbv = *(const short8*)&wT[(size_t)(j0 + row) * 512 + k0 + c8];
        }
        short8 af[2], bf[2];
        #pragma unroll
        for (int m = 0; m < 2; ++m)
            af[m] = *(const short8*)&As[wm * 32 + m * 16 + l15][l4 * 8];
        #pragma unroll
        for (int n = 0; n < 2; ++n)
            bf[n] = *(const short8*)&Bs[wn * 32 + n * 16 + l15][l4 * 8];
        #pragma unroll
        for (int m = 0; m < 2; ++m)
            #pragma unroll
            for (int n = 0; n < 2; ++n)
                acc[m][n] = mfma16(af[m], bf[n], acc[m][n]);
    }

    #pragma unroll
    for (int m = 0; m < 2; ++m)
        #pragma unroll
        for (int n = 0; n < 2; ++n) {
            int col = j0 + wn * 32 + n * 16 + l15;
            float bb = bias[col];
            #pragma unroll
            for (int r = 0; r < 4; ++r) {
                int row = i0 + wm * 32 + m * 16 + l4 * 4 + r;
                out[(size_t)row * 512 + col] = acc[m][n][r] + bb;
            }
        }
}

extern "C" void kernel_launch(void* const* d_in, const int* in_sizes, int n_in,
                              void* d_out, int out_size, void* d_ws, size_t ws_size,
                              hipStream_t stream) {
    const float* x         = (const float*)d_in[0];
    const float* spd       = (const float*)d_in[1];
    const float* head_keep = (const float*)d_in[2];
    const float* w_qkv     = (const float*)d_in[3];
    const float* w_out     = (const float*)d_in[4];
    const float* b_out     = (const float*)d_in[5];
    float* out = (float*)d_out;

    char* ws = (char*)d_ws;
    u16* x_bf   = (u16*)(ws);                       // 4096*512
    u16* wqkvT  = (u16*)(ws + (4u << 20));          // 1536*512
    u16* woutT  = (u16*)(ws + (4u << 20) + 1572864);// 512*512
    u16* qb     = (u16*)(ws + (6u << 20));          // 32*1024*64
    u16* kb     = (u16*)(ws + (10u << 20));
    u16* vT     = (u16*)(ws + (14u << 20));
    u16* ab     = (u16*)(ws + (18u << 20));         // 4096*512

    prep<<<1280, 256, 0, stream>>>(x, w_qkv, w_out, x_bf, wqkvT, woutT);
    gemm_qkv_mfma<<<dim3(24, 32), 256, 0, stream>>>(x_bf, wqkvT, qb, kb, vT);
    attn_mfma<<<dim3(8, 32), 256, 0, stream>>>(qb, kb, vT, spd, head_keep, ab);
    gemm_out_mfma<<<dim3(8, 64), 256, 0, stream>>>(ab, woutT, b_out, out);
}